// Round 1
// baseline (3705.631 us; speedup 1.0000x reference)
//
#include <hip/hip_runtime.h>
#include <math.h>

#define NN 100000
#define DD 128
#define CC 16
#define SS 16
#define EE 3200000
#define KK 64
#define NIT 4

// -------------------- init kernels --------------------

__global__ __launch_bounds__(256)
void k_norm(const float* __restrict__ es, double* __restrict__ inv_norm) {
    int wave = threadIdx.x >> 6, lane = threadIdx.x & 63;
    int n = blockIdx.x * 4 + wave;
    if (n >= NN) return;
    float a = es[(long)n * DD + lane];
    float b = es[(long)n * DD + 64 + lane];
    double p = (double)a * (double)a + (double)b * (double)b;
    for (int o = 32; o > 0; o >>= 1) p += __shfl_xor(p, o, 64);
    if (lane == 0) inv_norm[n] = 1.0 / (sqrt(p) + 1e-8);
}

__global__ __launch_bounds__(256)
void k_zero(int* __restrict__ known, unsigned* __restrict__ cate,
            unsigned* __restrict__ nbr) {
    int n = blockIdx.x * blockDim.x + threadIdx.x;
    if (n < NN) { known[n] = 0; cate[n] = 0; nbr[n] = 0; }
}

__global__ void k_seed(const int* __restrict__ seeds, int* __restrict__ known,
                       unsigned* __restrict__ cate) {
    int i = threadIdx.x;
    if (i < CC * SS) {
        int n = seeds[i];
        known[n] = 1;
        atomicOr(&cate[n], 1u << (i / SS));
    }
}

__global__ void k_zcnt(int* __restrict__ cnt) {
    if (threadIdx.x < CC) cnt[threadIdx.x] = 0;
}

// -------------------- memory step (attention + GRU-ish update), fp64 --------------------

__global__ __launch_bounds__(128)
void k_mem(const float* __restrict__ es, const float* __restrict__ Wm,
           const int* __restrict__ seeds, const int* __restrict__ last,
           double* __restrict__ hx, double* __restrict__ hxn,
           float* __restrict__ out, int t) {
    __shared__ float  inp[KK][DD];   // gathered rows (f32), 32KB
    __shared__ double q[DD];
    __shared__ double lg[KK];
    __shared__ double pre[DD];
    __shared__ double red[DD];
    int c = blockIdx.x, tid = threadIdx.x;
    int k = (t == 0) ? SS : KK;
    const int* rows = (t == 0) ? (seeds + c * SS) : (last + c * KK);
    for (int j = 0; j < k; ++j) inp[j][tid] = es[(long)rows[j] * DD + tid];
    __syncthreads();
    if (t == 0) {
        double s = 0;
        for (int j = 0; j < k; ++j) s += (double)inp[j][tid];
        q[tid] = s / (double)k;
    } else {
        q[tid] = hx[c * DD + tid];
    }
    __syncthreads();
    if (tid < k) {
        double s = 0;
        for (int i = 0; i < DD; ++i) s += (double)inp[tid][i] * q[i];
        lg[tid] = s / sqrt((double)DD);
    }
    __syncthreads();
    if (tid == 0) {
        double mx = lg[0];
        for (int j = 1; j < k; ++j) mx = fmax(mx, lg[j]);
        double sm = 0;
        for (int j = 0; j < k; ++j) { lg[j] = exp(lg[j] - mx); sm += lg[j]; }
        for (int j = 0; j < k; ++j) lg[j] /= sm;
    }
    __syncthreads();
    double ctx = 0;
    for (int j = 0; j < k; ++j) ctx += lg[j] * (double)inp[j][tid];
    double pv = (t == 0) ? ctx : (ctx + q[tid]);   // q == prev hx when t>0
    pre[tid] = pv;
    __syncthreads();
    double h = 0;
    for (int i = 0; i < DD; ++i) h += pre[i] * (double)Wm[i * DD + tid];
    h = tanh(h);
    red[tid] = h * h;
    __syncthreads();
    for (int st = 64; st > 0; st >>= 1) {
        if (tid < st) red[tid] += red[tid + st];
        __syncthreads();
    }
    double inv = 1.0 / (sqrt(red[0]) + 1e-8);
    hx[c * DD + tid] = h;
    hxn[c * DD + tid] = h * inv;
    out[2 * NIT * CC * KK + t * CC * DD + c * DD + tid] = (float)h;  // hxes
}

// -------------------- edge pass: nbr[dst] |= cate[src] --------------------

__global__ __launch_bounds__(256)
void k_edge(const int* __restrict__ edge, const unsigned* __restrict__ cate,
            unsigned* __restrict__ nbr) {
    long e = (long)blockIdx.x * blockDim.x + threadIdx.x;
    if (e >= EE) return;
    int s = edge[e];
    unsigned m = cate[s];
    if (m) {
        int d = edge[EE + e];
        atomicOr(&nbr[d], m);
    }
}

// -------------------- candidate scoring: one wave per node --------------------

__global__ __launch_bounds__(256)
void k_cand(const float* __restrict__ es, const double* __restrict__ inv_norm,
            const int* __restrict__ known, const unsigned* __restrict__ nbr,
            const double* __restrict__ hxn,
            int* __restrict__ cnt, int* __restrict__ cidx,
            double* __restrict__ cscore, int cap) {
    int wave = threadIdx.x >> 6, lane = threadIdx.x & 63;
    int n = blockIdx.x * 4 + wave;
    if (n >= NN) return;
    if (known[n]) return;
    unsigned m = nbr[n];
    if (!m) return;
    float e0 = es[(long)n * DD + lane];
    float e1 = es[(long)n * DD + 64 + lane];
    double invn = inv_norm[n];
    while (m) {
        int c = __ffs(m) - 1;
        m &= m - 1;
        double p = (double)e0 * hxn[c * DD + lane] + (double)e1 * hxn[c * DD + 64 + lane];
        for (int o = 32; o > 0; o >>= 1) p += __shfl_xor(p, o, 64);
        if (lane == 0) {
            int pos = atomicAdd(&cnt[c], 1);
            if (pos < cap) {
                cidx[(long)c * cap + pos] = n;
                cscore[(long)c * cap + pos] = p * invn;
            }
        }
    }
}

// -------------------- exact top-K (desc value, tie -> lower index) --------------------

__global__ __launch_bounds__(256)
void k_sel(const int* __restrict__ cnt, const int* __restrict__ cidx,
           double* __restrict__ cscore, const int* __restrict__ known,
           const unsigned* __restrict__ nbr,
           int* __restrict__ sel_idx, double* __restrict__ sel_prob, int cap) {
    int c = blockIdx.x, tid = threadIdx.x;
    int count = min(cnt[c], cap);
    __shared__ double bs[256];
    __shared__ int    bn[256];
    __shared__ int    bp[256];
    int nsel = min(count, KK);
    for (int r = 0; r < nsel; ++r) {
        double best = -1e300; int bnode = 0x7fffffff; int bpos = -1;
        for (int i = tid; i < count; i += 256) {
            double s = cscore[(long)c * cap + i];
            int node = cidx[(long)c * cap + i];
            if (s > best || (s == best && node < bnode)) { best = s; bnode = node; bpos = i; }
        }
        bs[tid] = best; bn[tid] = bnode; bp[tid] = bpos;
        __syncthreads();
        for (int st = 128; st > 0; st >>= 1) {
            if (tid < st) {
                if (bs[tid + st] > bs[tid] ||
                    (bs[tid + st] == bs[tid] && bn[tid + st] < bn[tid])) {
                    bs[tid] = bs[tid + st]; bn[tid] = bn[tid + st]; bp[tid] = bp[tid + st];
                }
            }
            __syncthreads();
        }
        if (tid == 0) {
            sel_idx[c * KK + r] = bn[0];
            sel_prob[c * KK + r] = bs[0];
            cscore[(long)c * cap + bp[0]] = -1e308;   // remove
        }
        __syncthreads();
    }
    // fill path (only if fewer valid than K): lowest-index invalid nodes, prob=-1e9
    if (tid == 0 && nsel < KK) {
        int r = nsel;
        for (int n = 0; n < NN && r < KK; ++n) {
            bool valid = ((nbr[n] >> c) & 1u) && !known[n];
            if (!valid) { sel_idx[c * KK + r] = n; sel_prob[c * KK + r] = -1e9; ++r; }
        }
    }
}

// -------------------- apply selections + write outputs --------------------

__global__ __launch_bounds__(256)
void k_upd(const int* __restrict__ sel_idx, const double* __restrict__ sel_prob,
           int* __restrict__ known, unsigned* __restrict__ cate,
           int* __restrict__ last, float* __restrict__ out, int t) {
    int i = blockIdx.x * blockDim.x + threadIdx.x;
    if (i >= CC * KK) return;
    int c = i / KK;
    int n = sel_idx[i];
    known[n] = 1;
    atomicOr(&cate[n], 1u << c);
    last[i] = n;
    out[t * CC * KK + i] = (float)sel_prob[i];               // outs
    out[NIT * CC * KK + t * CC * KK + i] = (float)n;         // exps as float
}

// -------------------- host launcher --------------------

extern "C" void kernel_launch(void* const* d_in, const int* in_sizes, int n_in,
                              void* d_out, int out_size, void* d_ws, size_t ws_size,
                              hipStream_t stream) {
    const float* es    = (const float*)d_in[0];
    const int*   edge  = (const int*)d_in[1];
    const int*   seeds = (const int*)d_in[2];
    const float* W     = (const float*)d_in[3];
    float* out = (float*)d_out;

    char* p = (char*)d_ws;
    auto alloc = [&](size_t bytes) -> char* {
        char* r = p;
        p += (bytes + 255) & ~(size_t)255;
        return r;
    };
    double*   inv_norm = (double*)alloc((size_t)NN * 8);
    int*      known    = (int*)alloc((size_t)NN * 4);
    unsigned* cate     = (unsigned*)alloc((size_t)NN * 4);
    unsigned* nbr      = (unsigned*)alloc((size_t)NN * 4);
    double*   hx       = (double*)alloc(CC * DD * 8);
    double*   hxn      = (double*)alloc(CC * DD * 8);
    int*      last     = (int*)alloc(CC * KK * 4);
    int*      sel_idx  = (int*)alloc(CC * KK * 4);
    double*   sel_prob = (double*)alloc(CC * KK * 8);
    int*      cnt      = (int*)alloc(64 * 4);
    size_t used = (size_t)(p - (char*)d_ws);
    size_t rem = (ws_size > used + 8192) ? (ws_size - used - 8192) : 0;
    long capl = (long)(rem / (CC * 12));
    if (capl > NN) capl = NN;
    if (capl < 1) capl = 1;
    int cap = (int)capl;
    int*    cidx   = (int*)alloc((size_t)CC * cap * 4);
    double* cscore = (double*)alloc((size_t)CC * cap * 8);

    k_norm<<<(NN + 3) / 4, 256, 0, stream>>>(es, inv_norm);
    k_zero<<<(NN + 255) / 256, 256, 0, stream>>>(known, cate, nbr);
    k_seed<<<1, 256, 0, stream>>>(seeds, known, cate);

    for (int t = 0; t < NIT; ++t) {
        k_mem<<<CC, 128, 0, stream>>>(es, W, seeds, last, hx, hxn, out, t);
        k_edge<<<(EE + 255) / 256, 256, 0, stream>>>(edge, cate, nbr);
        k_zcnt<<<1, 64, 0, stream>>>(cnt);
        k_cand<<<(NN + 3) / 4, 256, 0, stream>>>(es, inv_norm, known, nbr, hxn,
                                                 cnt, cidx, cscore, cap);
        k_sel<<<CC, 256, 0, stream>>>(cnt, cidx, cscore, known, nbr,
                                      sel_idx, sel_prob, cap);
        k_upd<<<4, 256, 0, stream>>>(sel_idx, sel_prob, known, cate, last, out, t);
    }
}

// Round 2
// 1332.002 us; speedup vs baseline: 2.7820x; 2.7820x over previous
//
#include <hip/hip_runtime.h>
#include <math.h>

#define NN 100000
#define DD 128
#define CC 16
#define SS 16
#define EE 3200000
#define KK 64
#define NIT 4
#define CNT_STRIDE 32   // pad class counters 128B apart

// -------------------- init kernels --------------------

__global__ __launch_bounds__(256)
void k_norm(const float* __restrict__ es, double* __restrict__ inv_norm) {
    int wave = threadIdx.x >> 6, lane = threadIdx.x & 63;
    int n = blockIdx.x * 4 + wave;
    if (n >= NN) return;
    float a = es[(long)n * DD + lane];
    float b = es[(long)n * DD + 64 + lane];
    double p = (double)a * (double)a + (double)b * (double)b;
    for (int o = 32; o > 0; o >>= 1) p += __shfl_xor(p, o, 64);
    if (lane == 0) inv_norm[n] = 1.0 / (sqrt(p) + 1e-8);
}

__global__ __launch_bounds__(256)
void k_zero(int* __restrict__ known, unsigned* __restrict__ cate,
            unsigned* __restrict__ nbr) {
    int n = blockIdx.x * blockDim.x + threadIdx.x;
    if (n < NN) { known[n] = 0; cate[n] = 0; nbr[n] = 0; }
}

__global__ void k_seed(const int* __restrict__ seeds, int* __restrict__ known,
                       unsigned* __restrict__ cate) {
    int i = threadIdx.x;
    if (i < CC * SS) {
        int n = seeds[i];
        known[n] = 1;
        atomicOr(&cate[n], 1u << (i / SS));
    }
}

__global__ void k_zcnt(int* __restrict__ cnt) {
    int i = blockIdx.x * blockDim.x + threadIdx.x;
    if (i < CC * CNT_STRIDE) cnt[i] = 0;
}

// -------------------- memory step (attention + recurrent update), fp64 --------------------

__global__ __launch_bounds__(128)
void k_mem(const float* __restrict__ es, const float* __restrict__ Wm,
           const int* __restrict__ seeds, const int* __restrict__ last,
           double* __restrict__ hx, double* __restrict__ hxn,
           float* __restrict__ out, int t) {
    __shared__ float  inp[KK][DD];
    __shared__ double q[DD];
    __shared__ double lg[KK];
    __shared__ double pre[DD];
    __shared__ double red[DD];
    int c = blockIdx.x, tid = threadIdx.x;
    int k = (t == 0) ? SS : KK;
    const int* rows = (t == 0) ? (seeds + c * SS) : (last + c * KK);
    for (int j = 0; j < k; ++j) inp[j][tid] = es[(long)rows[j] * DD + tid];
    __syncthreads();
    if (t == 0) {
        double s = 0;
        for (int j = 0; j < k; ++j) s += (double)inp[j][tid];
        q[tid] = s / (double)k;
    } else {
        q[tid] = hx[c * DD + tid];
    }
    __syncthreads();
    if (tid < k) {
        double s = 0;
        for (int i = 0; i < DD; ++i) s += (double)inp[tid][i] * q[i];
        lg[tid] = s / sqrt((double)DD);
    }
    __syncthreads();
    if (tid == 0) {
        double mx = lg[0];
        for (int j = 1; j < k; ++j) mx = fmax(mx, lg[j]);
        double sm = 0;
        for (int j = 0; j < k; ++j) { lg[j] = exp(lg[j] - mx); sm += lg[j]; }
        for (int j = 0; j < k; ++j) lg[j] /= sm;
    }
    __syncthreads();
    double ctx = 0;
    for (int j = 0; j < k; ++j) ctx += lg[j] * (double)inp[j][tid];
    double pv = (t == 0) ? ctx : (ctx + q[tid]);
    pre[tid] = pv;
    __syncthreads();
    double h = 0;
    for (int i = 0; i < DD; ++i) h += pre[i] * (double)Wm[i * DD + tid];
    h = tanh(h);
    red[tid] = h * h;
    __syncthreads();
    for (int st = 64; st > 0; st >>= 1) {
        if (tid < st) red[tid] += red[tid + st];
        __syncthreads();
    }
    double inv = 1.0 / (sqrt(red[0]) + 1e-8);
    hx[c * DD + tid] = h;
    hxn[c * DD + tid] = h * inv;
    out[2 * NIT * CC * KK + t * CC * DD + c * DD + tid] = (float)h;  // hxes
}

// -------------------- edge pass: nbr[dst] |= cate[src] --------------------

__global__ __launch_bounds__(256)
void k_edge(const int* __restrict__ edge, const unsigned* __restrict__ cate,
            unsigned* __restrict__ nbr) {
    long e = (long)blockIdx.x * blockDim.x + threadIdx.x;
    if (e >= EE) return;
    int s = edge[e];
    unsigned m = cate[s];
    if (m) {
        int d = edge[EE + e];
        atomicOr(&nbr[d], m);
    }
}

// -------------------- candidate scoring: block-aggregated, thread-per-pair --------------------

__global__ __launch_bounds__(256)
void k_cand(const float* __restrict__ es, const double* __restrict__ inv_norm,
            const int* __restrict__ known, const unsigned* __restrict__ nbr,
            const double* __restrict__ hxn,
            int* __restrict__ cnt, int* __restrict__ cidx,
            double* __restrict__ cscore, int cap) {
    __shared__ int    pair[256 * 16];      // packed (n<<4)|c, 16KB
    __shared__ short  prank[256 * 16];     // per-class local rank, 8KB
    __shared__ double hxnL[CC * 129];      // padded hxn, ~16.5KB
    __shared__ int    lcnt[CC];
    __shared__ int    base[CC];
    __shared__ int    npair;
    int tid = threadIdx.x;

    // stage normalized hx into LDS (padded row stride 129 -> conflict-free)
    for (int i = tid; i < CC * DD; i += 256)
        hxnL[(i >> 7) * 129 + (i & 127)] = hxn[i];
    if (tid < CC) lcnt[tid] = 0;
    if (tid == 0) npair = 0;
    __syncthreads();

    // phase 1: filter + expand pairs into LDS
    int n = blockIdx.x * 256 + tid;
    unsigned m = 0;
    if (n < NN && !known[n]) m = nbr[n];
    while (m) {
        int c = __ffs(m) - 1;
        m &= m - 1;
        int r = atomicAdd(&lcnt[c], 1);
        int p = atomicAdd(&npair, 1);
        pair[p] = (n << 4) | c;
        prank[p] = (short)r;
    }
    __syncthreads();

    // phase 2: one global atomic per class per block
    if (tid < CC && lcnt[tid] > 0)
        base[tid] = atomicAdd(&cnt[tid * CNT_STRIDE], lcnt[tid]);
    __syncthreads();

    // phase 3: score pairs, thread-per-pair (fp64 dot over 128)
    int np = npair;
    for (int t2 = tid; t2 < np; t2 += 256) {
        int pk = pair[t2];
        int nn = pk >> 4, c = pk & 15;
        const float4* row = (const float4*)(es + (long)nn * DD);
        const double* h = &hxnL[c * 129];
        double s = 0;
        #pragma unroll
        for (int i = 0; i < 32; ++i) {
            float4 v = row[i];
            s += (double)v.x * h[4 * i + 0] + (double)v.y * h[4 * i + 1]
               + (double)v.z * h[4 * i + 2] + (double)v.w * h[4 * i + 3];
        }
        int pos = base[c] + (int)prank[t2];
        if (pos < cap) {
            cidx[(long)c * cap + pos] = nn;
            cscore[(long)c * cap + pos] = s * inv_norm[nn];
        }
    }
}

// -------------------- exact top-K (desc value, tie -> lower index) --------------------

__global__ __launch_bounds__(256)
void k_sel(const int* __restrict__ cnt, const int* __restrict__ cidx,
           double* __restrict__ cscore, const int* __restrict__ known,
           const unsigned* __restrict__ nbr,
           int* __restrict__ sel_idx, double* __restrict__ sel_prob, int cap) {
    int c = blockIdx.x, tid = threadIdx.x;
    int count = min(cnt[c * CNT_STRIDE], cap);
    __shared__ double bs[256];
    __shared__ int    bn[256];
    __shared__ int    bp[256];
    int nsel = min(count, KK);
    for (int r = 0; r < nsel; ++r) {
        double best = -1e300; int bnode = 0x7fffffff; int bpos = -1;
        for (int i = tid; i < count; i += 256) {
            double s = cscore[(long)c * cap + i];
            int node = cidx[(long)c * cap + i];
            if (s > best || (s == best && node < bnode)) { best = s; bnode = node; bpos = i; }
        }
        bs[tid] = best; bn[tid] = bnode; bp[tid] = bpos;
        __syncthreads();
        for (int st = 128; st > 0; st >>= 1) {
            if (tid < st) {
                if (bs[tid + st] > bs[tid] ||
                    (bs[tid + st] == bs[tid] && bn[tid + st] < bn[tid])) {
                    bs[tid] = bs[tid + st]; bn[tid] = bn[tid + st]; bp[tid] = bp[tid + st];
                }
            }
            __syncthreads();
        }
        if (tid == 0) {
            sel_idx[c * KK + r] = bn[0];
            sel_prob[c * KK + r] = bs[0];
            cscore[(long)c * cap + bp[0]] = -1e308;
        }
        __syncthreads();
    }
    if (tid == 0 && nsel < KK) {
        int r = nsel;
        for (int n = 0; n < NN && r < KK; ++n) {
            bool valid = ((nbr[n] >> c) & 1u) && !known[n];
            if (!valid) { sel_idx[c * KK + r] = n; sel_prob[c * KK + r] = -1e9; ++r; }
        }
    }
}

// -------------------- apply selections + write outputs --------------------

__global__ __launch_bounds__(256)
void k_upd(const int* __restrict__ sel_idx, const double* __restrict__ sel_prob,
           int* __restrict__ known, unsigned* __restrict__ cate,
           int* __restrict__ last, float* __restrict__ out, int t) {
    int i = blockIdx.x * blockDim.x + threadIdx.x;
    if (i >= CC * KK) return;
    int c = i / KK;
    int n = sel_idx[i];
    known[n] = 1;
    atomicOr(&cate[n], 1u << c);
    last[i] = n;
    out[t * CC * KK + i] = (float)sel_prob[i];               // outs
    out[NIT * CC * KK + t * CC * KK + i] = (float)n;         // exps as float
}

// -------------------- host launcher --------------------

extern "C" void kernel_launch(void* const* d_in, const int* in_sizes, int n_in,
                              void* d_out, int out_size, void* d_ws, size_t ws_size,
                              hipStream_t stream) {
    const float* es    = (const float*)d_in[0];
    const int*   edge  = (const int*)d_in[1];
    const int*   seeds = (const int*)d_in[2];
    const float* W     = (const float*)d_in[3];
    float* out = (float*)d_out;

    char* p = (char*)d_ws;
    auto alloc = [&](size_t bytes) -> char* {
        char* r = p;
        p += (bytes + 255) & ~(size_t)255;
        return r;
    };
    double*   inv_norm = (double*)alloc((size_t)NN * 8);
    int*      known    = (int*)alloc((size_t)NN * 4);
    unsigned* cate     = (unsigned*)alloc((size_t)NN * 4);
    unsigned* nbr      = (unsigned*)alloc((size_t)NN * 4);
    double*   hx       = (double*)alloc(CC * DD * 8);
    double*   hxn      = (double*)alloc(CC * DD * 8);
    int*      last     = (int*)alloc(CC * KK * 4);
    int*      sel_idx  = (int*)alloc(CC * KK * 4);
    double*   sel_prob = (double*)alloc(CC * KK * 8);
    int*      cnt      = (int*)alloc(CC * CNT_STRIDE * 4);
    size_t used = (size_t)(p - (char*)d_ws);
    size_t rem = (ws_size > used + 8192) ? (ws_size - used - 8192) : 0;
    long capl = (long)(rem / (CC * 12));
    if (capl > NN) capl = NN;
    if (capl < 1) capl = 1;
    int cap = (int)capl;
    int*    cidx   = (int*)alloc((size_t)CC * cap * 4);
    double* cscore = (double*)alloc((size_t)CC * cap * 8);

    k_norm<<<(NN + 3) / 4, 256, 0, stream>>>(es, inv_norm);
    k_zero<<<(NN + 255) / 256, 256, 0, stream>>>(known, cate, nbr);
    k_seed<<<1, 256, 0, stream>>>(seeds, known, cate);

    for (int t = 0; t < NIT; ++t) {
        k_mem<<<CC, 128, 0, stream>>>(es, W, seeds, last, hx, hxn, out, t);
        k_edge<<<(EE + 255) / 256, 256, 0, stream>>>(edge, cate, nbr);
        k_zcnt<<<1, CC * CNT_STRIDE, 0, stream>>>(cnt);
        k_cand<<<(NN + 255) / 256, 256, 0, stream>>>(es, inv_norm, known, nbr, hxn,
                                                     cnt, cidx, cscore, cap);
        k_sel<<<CC, 256, 0, stream>>>(cnt, cidx, cscore, known, nbr,
                                      sel_idx, sel_prob, cap);
        k_upd<<<4, 256, 0, stream>>>(sel_idx, sel_prob, known, cate, last, out, t);
    }
}

// Round 3
// 866.960 us; speedup vs baseline: 4.2743x; 1.5364x over previous
//
#include <hip/hip_runtime.h>
#include <math.h>

#define NN 100000
#define DD 128
#define CC 16
#define SS 16
#define EE 3200000
#define KK 64
#define NIT 4
#define CNT_STRIDE 32   // pad class counters 128B apart
#define NB 32           // stage-A blocks per class
#define SLMAX 4096      // max stage-A slice (pow2 >= ceil(NN/NB)=3125)
#define MM (NB * KK)    // stage-B merge size = 2048

// order-preserving double -> uint64 bijection (and exact inverse)
__device__ inline unsigned long long ordkey(double d) {
    long long b = __double_as_longlong(d);
    return (b < 0) ? ~(unsigned long long)b
                   : ((unsigned long long)b | 0x8000000000000000ULL);
}
__device__ inline double keyord(unsigned long long u) {
    long long b = (u & 0x8000000000000000ULL)
                    ? (long long)(u & 0x7FFFFFFFFFFFFFFFULL)
                    : (long long)~u;
    return __longlong_as_double(b);
}

// -------------------- init kernels --------------------

__global__ __launch_bounds__(256)
void k_norm(const float* __restrict__ es, double* __restrict__ inv_norm) {
    int wave = threadIdx.x >> 6, lane = threadIdx.x & 63;
    int n = blockIdx.x * 4 + wave;
    if (n >= NN) return;
    float a = es[(long)n * DD + lane];
    float b = es[(long)n * DD + 64 + lane];
    double p = (double)a * (double)a + (double)b * (double)b;
    for (int o = 32; o > 0; o >>= 1) p += __shfl_xor(p, o, 64);
    if (lane == 0) inv_norm[n] = 1.0 / (sqrt(p) + 1e-8);
}

__global__ __launch_bounds__(256)
void k_zero(int* __restrict__ known, unsigned* __restrict__ cate,
            unsigned* __restrict__ nbr) {
    int n = blockIdx.x * blockDim.x + threadIdx.x;
    if (n < NN) { known[n] = 0; cate[n] = 0; nbr[n] = 0; }
}

__global__ void k_seed(const int* __restrict__ seeds, int* __restrict__ known,
                       unsigned* __restrict__ cate) {
    int i = threadIdx.x;
    if (i < CC * SS) {
        int n = seeds[i];
        known[n] = 1;
        atomicOr(&cate[n], 1u << (i / SS));
    }
}

__global__ void k_zcnt(int* __restrict__ cnt) {
    int i = blockIdx.x * blockDim.x + threadIdx.x;
    if (i < CC * CNT_STRIDE) cnt[i] = 0;
}

// -------------------- memory step (attention + recurrent update), fp64 --------------------

__global__ __launch_bounds__(128)
void k_mem(const float* __restrict__ es, const float* __restrict__ Wm,
           const int* __restrict__ seeds, const int* __restrict__ last,
           double* __restrict__ hx, double* __restrict__ hxn,
           float* __restrict__ out, int t) {
    __shared__ float  inp[KK][DD];
    __shared__ double q[DD];
    __shared__ double lg[KK];
    __shared__ double pre[DD];
    __shared__ double red[DD];
    int c = blockIdx.x, tid = threadIdx.x;
    int k = (t == 0) ? SS : KK;
    const int* rows = (t == 0) ? (seeds + c * SS) : (last + c * KK);
    for (int j = 0; j < k; ++j) inp[j][tid] = es[(long)rows[j] * DD + tid];
    __syncthreads();
    if (t == 0) {
        double s = 0;
        for (int j = 0; j < k; ++j) s += (double)inp[j][tid];
        q[tid] = s / (double)k;
    } else {
        q[tid] = hx[c * DD + tid];
    }
    __syncthreads();
    if (tid < k) {
        double s = 0;
        for (int i = 0; i < DD; ++i) s += (double)inp[tid][i] * q[i];
        lg[tid] = s / sqrt((double)DD);
    }
    __syncthreads();
    if (tid == 0) {
        double mx = lg[0];
        for (int j = 1; j < k; ++j) mx = fmax(mx, lg[j]);
        double sm = 0;
        for (int j = 0; j < k; ++j) { lg[j] = exp(lg[j] - mx); sm += lg[j]; }
        for (int j = 0; j < k; ++j) lg[j] /= sm;
    }
    __syncthreads();
    double ctx = 0;
    for (int j = 0; j < k; ++j) ctx += lg[j] * (double)inp[j][tid];
    double pv = (t == 0) ? ctx : (ctx + q[tid]);
    pre[tid] = pv;
    __syncthreads();
    double h = 0;
    for (int i = 0; i < DD; ++i) h += pre[i] * (double)Wm[i * DD + tid];
    h = tanh(h);
    red[tid] = h * h;
    __syncthreads();
    for (int st = 64; st > 0; st >>= 1) {
        if (tid < st) red[tid] += red[tid + st];
        __syncthreads();
    }
    double inv = 1.0 / (sqrt(red[0]) + 1e-8);
    hx[c * DD + tid] = h;
    hxn[c * DD + tid] = h * inv;
    out[2 * NIT * CC * KK + t * CC * DD + c * DD + tid] = (float)h;  // hxes
}

// -------------------- edge pass: nbr[dst] |= cate[src] --------------------

__global__ __launch_bounds__(256)
void k_edge(const int* __restrict__ edge, const unsigned* __restrict__ cate,
            unsigned* __restrict__ nbr) {
    long e = (long)blockIdx.x * blockDim.x + threadIdx.x;
    if (e >= EE) return;
    int s = edge[e];
    unsigned m = cate[s];
    if (m) {
        int d = edge[EE + e];
        atomicOr(&nbr[d], m);
    }
}

// -------------------- candidate scoring: block-aggregated, thread-per-pair --------------------

__global__ __launch_bounds__(256)
void k_cand(const float* __restrict__ es, const double* __restrict__ inv_norm,
            const int* __restrict__ known, const unsigned* __restrict__ nbr,
            const double* __restrict__ hxn,
            int* __restrict__ cnt, int* __restrict__ cidx,
            double* __restrict__ cscore, int cap) {
    __shared__ int    pair[256 * 16];      // packed (n<<4)|c
    __shared__ short  prank[256 * 16];     // per-class local rank
    __shared__ double hxnL[CC * 129];      // padded hxn
    __shared__ int    lcnt[CC];
    __shared__ int    base[CC];
    __shared__ int    npair;
    int tid = threadIdx.x;

    for (int i = tid; i < CC * DD; i += 256)
        hxnL[(i >> 7) * 129 + (i & 127)] = hxn[i];
    if (tid < CC) lcnt[tid] = 0;
    if (tid == 0) npair = 0;
    __syncthreads();

    int n = blockIdx.x * 256 + tid;
    unsigned m = 0;
    if (n < NN && !known[n]) m = nbr[n];
    while (m) {
        int c = __ffs(m) - 1;
        m &= m - 1;
        int r = atomicAdd(&lcnt[c], 1);
        int p = atomicAdd(&npair, 1);
        pair[p] = (n << 4) | c;
        prank[p] = (short)r;
    }
    __syncthreads();

    if (tid < CC && lcnt[tid] > 0)
        base[tid] = atomicAdd(&cnt[tid * CNT_STRIDE], lcnt[tid]);
    __syncthreads();

    int np = npair;
    for (int t2 = tid; t2 < np; t2 += 256) {
        int pk = pair[t2];
        int nn = pk >> 4, c = pk & 15;
        const float4* row = (const float4*)(es + (long)nn * DD);
        const double* h = &hxnL[c * 129];
        double s = 0;
        #pragma unroll
        for (int i = 0; i < 32; ++i) {
            float4 v = row[i];
            s += (double)v.x * h[4 * i + 0] + (double)v.y * h[4 * i + 1]
               + (double)v.z * h[4 * i + 2] + (double)v.w * h[4 * i + 3];
        }
        int pos = base[c] + (int)prank[t2];
        if (pos < cap) {
            cidx[(long)c * cap + pos] = nn;
            cscore[(long)c * cap + pos] = s * inv_norm[nn];
        }
    }
}

// -------------------- stage A: per-slice exact top-64 via LDS bitonic sort --------------------

__global__ __launch_bounds__(256)
void k_top(const int* __restrict__ cnt, const int* __restrict__ cidx,
           const double* __restrict__ cscore, int cap,
           unsigned long long* __restrict__ tkey, int* __restrict__ tnode) {
    __shared__ unsigned long long ks[SLMAX];
    __shared__ int ns[SLMAX];
    int c = blockIdx.x / NB, b = blockIdx.x % NB, tid = threadIdx.x;
    int count = min(cnt[c * CNT_STRIDE], cap);
    int per = (count + NB - 1) / NB;          // <= 3125
    int start = b * per;
    int m = min(per, count - start);          // may be <= 0
    int sl = 64;
    while (sl < per) sl <<= 1;                // <= SLMAX
    for (int i = tid; i < sl; i += 256) {
        if (i < m) {
            ks[i] = ordkey(cscore[(long)c * cap + start + i]);
            ns[i] = cidx[(long)c * cap + start + i];
        } else { ks[i] = 0ULL; ns[i] = 0x7FFFFFFF; }
    }
    __syncthreads();
    // bitonic sort: "earlier" = higher key, tie -> lower node (== lax.top_k order)
    for (int k2 = 2; k2 <= sl; k2 <<= 1) {
        for (int j = k2 >> 1; j > 0; j >>= 1) {
            for (int i = tid; i < sl; i += 256) {
                int p = i ^ j;
                if (p > i) {
                    bool up = ((i & k2) == 0);
                    unsigned long long ki = ks[i], kp = ks[p];
                    int ni = ns[i], np2 = ns[p];
                    bool sw = up ? ((kp > ki) || (kp == ki && np2 < ni))
                                 : ((ki > kp) || (ki == kp && ni < np2));
                    if (sw) { ks[i] = kp; ks[p] = ki; ns[i] = np2; ns[p] = ni; }
                }
            }
            __syncthreads();
        }
    }
    for (int i = tid; i < KK; i += 256) {
        tkey[(long)c * MM + b * KK + i] = ks[i];
        tnode[(long)c * MM + b * KK + i] = ns[i];
    }
}

// -------------------- stage B: merge 32x64 winners, emit exact top-64 --------------------

__global__ __launch_bounds__(256)
void k_merge(const int* __restrict__ cnt,
             const unsigned long long* __restrict__ tkey,
             const int* __restrict__ tnode,
             const int* __restrict__ known, const unsigned* __restrict__ nbr,
             int* __restrict__ sel_idx, double* __restrict__ sel_prob, int cap) {
    __shared__ unsigned long long ks[MM];
    __shared__ int ns[MM];
    int c = blockIdx.x, tid = threadIdx.x;
    for (int i = tid; i < MM; i += 256) {
        ks[i] = tkey[(long)c * MM + i];
        ns[i] = tnode[(long)c * MM + i];
    }
    __syncthreads();
    for (int k2 = 2; k2 <= MM; k2 <<= 1) {
        for (int j = k2 >> 1; j > 0; j >>= 1) {
            for (int i = tid; i < MM; i += 256) {
                int p = i ^ j;
                if (p > i) {
                    bool up = ((i & k2) == 0);
                    unsigned long long ki = ks[i], kp = ks[p];
                    int ni = ns[i], np2 = ns[p];
                    bool sw = up ? ((kp > ki) || (kp == ki && np2 < ni))
                                 : ((ki > kp) || (ki == kp && ni < np2));
                    if (sw) { ks[i] = kp; ks[p] = ki; ns[i] = np2; ns[p] = ni; }
                }
            }
            __syncthreads();
        }
    }
    int count = min(cnt[c * CNT_STRIDE], cap);
    int nsel = min(count, KK);
    for (int i = tid; i < KK; i += 256) {
        if (i < nsel) {
            sel_idx[c * KK + i] = ns[i];
            sel_prob[c * KK + i] = keyord(ks[i]);
        }
    }
    // fill path (fewer valid than K): lowest-index invalid nodes, prob=-1e9
    if (tid == 0 && nsel < KK) {
        int r = nsel;
        for (int n = 0; n < NN && r < KK; ++n) {
            bool valid = ((nbr[n] >> c) & 1u) && !known[n];
            if (!valid) { sel_idx[c * KK + r] = n; sel_prob[c * KK + r] = -1e9; ++r; }
        }
    }
}

// -------------------- apply selections + write outputs --------------------

__global__ __launch_bounds__(256)
void k_upd(const int* __restrict__ sel_idx, const double* __restrict__ sel_prob,
           int* __restrict__ known, unsigned* __restrict__ cate,
           int* __restrict__ last, float* __restrict__ out, int t) {
    int i = blockIdx.x * blockDim.x + threadIdx.x;
    if (i >= CC * KK) return;
    int c = i / KK;
    int n = sel_idx[i];
    known[n] = 1;
    atomicOr(&cate[n], 1u << c);
    last[i] = n;
    out[t * CC * KK + i] = (float)sel_prob[i];               // outs
    out[NIT * CC * KK + t * CC * KK + i] = (float)n;         // exps as float
}

// -------------------- host launcher --------------------

extern "C" void kernel_launch(void* const* d_in, const int* in_sizes, int n_in,
                              void* d_out, int out_size, void* d_ws, size_t ws_size,
                              hipStream_t stream) {
    const float* es    = (const float*)d_in[0];
    const int*   edge  = (const int*)d_in[1];
    const int*   seeds = (const int*)d_in[2];
    const float* W     = (const float*)d_in[3];
    float* out = (float*)d_out;

    char* p = (char*)d_ws;
    auto alloc = [&](size_t bytes) -> char* {
        char* r = p;
        p += (bytes + 255) & ~(size_t)255;
        return r;
    };
    double*   inv_norm = (double*)alloc((size_t)NN * 8);
    int*      known    = (int*)alloc((size_t)NN * 4);
    unsigned* cate     = (unsigned*)alloc((size_t)NN * 4);
    unsigned* nbr      = (unsigned*)alloc((size_t)NN * 4);
    double*   hx       = (double*)alloc(CC * DD * 8);
    double*   hxn      = (double*)alloc(CC * DD * 8);
    int*      last     = (int*)alloc(CC * KK * 4);
    int*      sel_idx  = (int*)alloc(CC * KK * 4);
    double*   sel_prob = (double*)alloc(CC * KK * 8);
    int*      cnt      = (int*)alloc(CC * CNT_STRIDE * 4);
    unsigned long long* tkey = (unsigned long long*)alloc((size_t)CC * MM * 8);
    int*      tnode    = (int*)alloc((size_t)CC * MM * 4);
    size_t used = (size_t)(p - (char*)d_ws);
    size_t rem = (ws_size > used + 8192) ? (ws_size - used - 8192) : 0;
    long capl = (long)(rem / (CC * 12));
    if (capl > NN) capl = NN;
    if (capl < 1) capl = 1;
    int cap = (int)capl;
    int*    cidx   = (int*)alloc((size_t)CC * cap * 4);
    double* cscore = (double*)alloc((size_t)CC * cap * 8);

    k_norm<<<(NN + 3) / 4, 256, 0, stream>>>(es, inv_norm);
    k_zero<<<(NN + 255) / 256, 256, 0, stream>>>(known, cate, nbr);
    k_seed<<<1, 256, 0, stream>>>(seeds, known, cate);

    for (int t = 0; t < NIT; ++t) {
        k_mem<<<CC, 128, 0, stream>>>(es, W, seeds, last, hx, hxn, out, t);
        k_edge<<<(EE + 255) / 256, 256, 0, stream>>>(edge, cate, nbr);
        k_zcnt<<<1, CC * CNT_STRIDE, 0, stream>>>(cnt);
        k_cand<<<(NN + 255) / 256, 256, 0, stream>>>(es, inv_norm, known, nbr, hxn,
                                                     cnt, cidx, cscore, cap);
        k_top<<<CC * NB, 256, 0, stream>>>(cnt, cidx, cscore, cap, tkey, tnode);
        k_merge<<<CC, 256, 0, stream>>>(cnt, tkey, tnode, known, nbr,
                                        sel_idx, sel_prob, cap);
        k_upd<<<4, 256, 0, stream>>>(sel_idx, sel_prob, known, cate, last, out, t);
    }
}

// Round 4
// 383.241 us; speedup vs baseline: 9.6692x; 2.2622x over previous
//
#include <hip/hip_runtime.h>
#include <math.h>

#define NN 100000
#define DD 128
#define CC 16
#define SS 16
#define EE 3200000
#define KK 64
#define NIT 4
#define CNT_STRIDE 32   // pad class counters 128B apart
#define NB 32           // stage-A blocks per class
#define SLMAX 4096      // max stage-A slice (pow2 >= ceil(NN/NB)=3125)
#define MM (NB * KK)    // stage-B merge size = 2048

typedef unsigned long long ull;

// order-preserving double -> uint64 bijection (and exact inverse)
__device__ inline ull ordkey(double d) {
    long long b = __double_as_longlong(d);
    return (b < 0) ? ~(ull)b : ((ull)b | 0x8000000000000000ULL);
}
__device__ inline double keyord(ull u) {
    long long b = (u & 0x8000000000000000ULL)
                    ? (long long)(u & 0x7FFFFFFFFFFFFFFFULL)
                    : (long long)~u;
    return __longlong_as_double(b);
}
// total order: "a earlier than b" == key desc, node asc (== lax.top_k order)
__device__ inline bool gt(ull ka, int na, ull kb, int nb) {
    return (ka > kb) || (ka == kb && na < nb);
}

// -------------------- init kernels --------------------

__global__ __launch_bounds__(256)
void k_norm(const float* __restrict__ es, double* __restrict__ inv_norm) {
    int wave = threadIdx.x >> 6, lane = threadIdx.x & 63;
    int n = blockIdx.x * 4 + wave;
    if (n >= NN) return;
    float a = es[(long)n * DD + lane];
    float b = es[(long)n * DD + 64 + lane];
    double p = (double)a * (double)a + (double)b * (double)b;
    for (int o = 32; o > 0; o >>= 1) p += __shfl_xor(p, o, 64);
    if (lane == 0) inv_norm[n] = 1.0 / (sqrt(p) + 1e-8);
}

__global__ __launch_bounds__(256)
void k_zero(int* __restrict__ known, unsigned* __restrict__ cate,
            unsigned* __restrict__ nbr) {
    int n = blockIdx.x * blockDim.x + threadIdx.x;
    if (n < NN) { known[n] = 0; cate[n] = 0; nbr[n] = 0; }
}

__global__ void k_seed(const int* __restrict__ seeds, int* __restrict__ known,
                       unsigned* __restrict__ cate) {
    int i = threadIdx.x;
    if (i < CC * SS) {
        int n = seeds[i];
        known[n] = 1;
        atomicOr(&cate[n], 1u << (i / SS));
    }
}

// -------------------- memory step (attention + recurrent update), fp64 --------------------

__global__ __launch_bounds__(128)
void k_mem(const float* __restrict__ es, const float* __restrict__ Wm,
           const int* __restrict__ seeds, const int* __restrict__ last,
           double* __restrict__ hx, double* __restrict__ hxn,
           float* __restrict__ out, int* __restrict__ cnt, int t) {
    __shared__ float  inp[KK][DD + 1];   // +1 pad: kills 64-way bank aliasing in logits dot
    __shared__ int    rowS[KK];
    __shared__ double q[DD];
    __shared__ double lg[KK];
    __shared__ double sr[KK];
    __shared__ double pre[DD];
    __shared__ double red[DD];
    int c = blockIdx.x, tid = threadIdx.x;
    if (tid == 0) cnt[c * CNT_STRIDE] = 0;          // fused k_zcnt
    int k = (t == 0) ? SS : KK;
    if (tid < KK) {
        lg[tid] = -1.0e308;
        if (tid < k) rowS[tid] = (t == 0) ? seeds[c * SS + tid] : last[c * KK + tid];
    }
    __syncthreads();
    for (int j = 0; j < k; ++j) inp[j][tid] = es[(long)rowS[j] * DD + tid];
    __syncthreads();
    if (t == 0) {
        double s = 0;
        for (int j = 0; j < k; ++j) s += (double)inp[j][tid];
        q[tid] = s / (double)k;
    } else {
        q[tid] = hx[c * DD + tid];
    }
    __syncthreads();
    if (tid < k) {
        double s = 0;
        for (int i = 0; i < DD; ++i) s += (double)inp[tid][i] * q[i];
        lg[tid] = s / sqrt((double)DD);
    }
    __syncthreads();
    if (tid < KK) sr[tid] = lg[tid];
    __syncthreads();
    for (int st = 32; st > 0; st >>= 1) {
        if (tid < st) sr[tid] = fmax(sr[tid], sr[tid + st]);
        __syncthreads();
    }
    double mx = sr[0];
    __syncthreads();
    if (tid < KK) {
        double e = (tid < k) ? exp(lg[tid] - mx) : 0.0;
        lg[tid] = e; sr[tid] = e;
    }
    __syncthreads();
    for (int st = 32; st > 0; st >>= 1) {
        if (tid < st) sr[tid] += sr[tid + st];
        __syncthreads();
    }
    double sm = sr[0];
    __syncthreads();
    if (tid < KK) lg[tid] /= sm;
    __syncthreads();
    double ctx = 0;
    for (int j = 0; j < k; ++j) ctx += lg[j] * (double)inp[j][tid];
    pre[tid] = (t == 0) ? ctx : (ctx + q[tid]);
    __syncthreads();
    double h = 0;
    for (int i = 0; i < DD; ++i) h += pre[i] * (double)Wm[i * DD + tid];
    h = tanh(h);
    red[tid] = h * h;
    __syncthreads();
    for (int st = 64; st > 0; st >>= 1) {
        if (tid < st) red[tid] += red[tid + st];
        __syncthreads();
    }
    double inv = 1.0 / (sqrt(red[0]) + 1e-8);
    hx[c * DD + tid] = h;
    hxn[c * DD + tid] = h * inv;
    out[2 * NIT * CC * KK + t * CC * DD + c * DD + tid] = (float)h;  // hxes
}

// -------------------- edge pass: nbr[dst] |= cate[src] --------------------

__global__ __launch_bounds__(256)
void k_edge(const int* __restrict__ edge, const unsigned* __restrict__ cate,
            unsigned* __restrict__ nbr) {
    long e = (long)blockIdx.x * blockDim.x + threadIdx.x;
    if (e >= EE) return;
    int s = edge[e];
    unsigned m = cate[s];
    if (m) {
        int d = edge[EE + e];
        atomicOr(&nbr[d], m);
    }
}

// -------------------- candidate scoring: block-aggregated, thread-per-pair --------------------

__global__ __launch_bounds__(256)
void k_cand(const float* __restrict__ es, const double* __restrict__ inv_norm,
            const int* __restrict__ known, const unsigned* __restrict__ nbr,
            const double* __restrict__ hxn,
            int* __restrict__ cnt, int* __restrict__ cidx,
            double* __restrict__ cscore, int cap) {
    __shared__ int    pair[256 * 16];
    __shared__ short  prank[256 * 16];
    __shared__ double hxnL[CC * 129];
    __shared__ int    lcnt[CC];
    __shared__ int    base[CC];
    __shared__ int    npair;
    int tid = threadIdx.x;

    for (int i = tid; i < CC * DD; i += 256)
        hxnL[(i >> 7) * 129 + (i & 127)] = hxn[i];
    if (tid < CC) lcnt[tid] = 0;
    if (tid == 0) npair = 0;
    __syncthreads();

    int n = blockIdx.x * 256 + tid;
    unsigned m = 0;
    if (n < NN && !known[n]) m = nbr[n];
    while (m) {
        int c = __ffs(m) - 1;
        m &= m - 1;
        int r = atomicAdd(&lcnt[c], 1);
        int p = atomicAdd(&npair, 1);
        pair[p] = (n << 4) | c;
        prank[p] = (short)r;
    }
    __syncthreads();

    if (tid < CC && lcnt[tid] > 0)
        base[tid] = atomicAdd(&cnt[tid * CNT_STRIDE], lcnt[tid]);
    __syncthreads();

    int np = npair;
    for (int t2 = tid; t2 < np; t2 += 256) {
        int pk = pair[t2];
        int nn = pk >> 4, c = pk & 15;
        const float4* row = (const float4*)(es + (long)nn * DD);
        const double* h = &hxnL[c * 129];
        double s = 0;
        #pragma unroll
        for (int i = 0; i < 32; ++i) {
            float4 v = row[i];
            s += (double)v.x * h[4 * i + 0] + (double)v.y * h[4 * i + 1]
               + (double)v.z * h[4 * i + 2] + (double)v.w * h[4 * i + 3];
        }
        int pos = base[c] + (int)prank[t2];
        if (pos < cap) {
            cidx[(long)c * cap + pos] = nn;
            cscore[(long)c * cap + pos] = s * inv_norm[nn];
        }
    }
}

// -------------------- stage A: per-slice exact top-64 (sort-64 + bitonic merge tree) ---------

__global__ __launch_bounds__(256)
void k_top(const int* __restrict__ cnt, const int* __restrict__ cidx,
           const double* __restrict__ cscore, int cap,
           ull* __restrict__ tkey, int* __restrict__ tnode) {
    __shared__ ull ks[SLMAX];
    __shared__ int ns[SLMAX];
    int c = blockIdx.x / NB, b = blockIdx.x % NB, tid = threadIdx.x;
    int count = min(cnt[c * CNT_STRIDE], cap);
    int per = (count + NB - 1) / NB;
    int start = b * per;
    int m = min(per, count - start);
    int sl = 64;
    while (sl < per) sl <<= 1;
    for (int i = tid; i < sl; i += 256) {
        if (i < m) {
            ks[i] = ordkey(cscore[(long)c * cap + start + i]);
            ns[i] = cidx[(long)c * cap + start + i];
        } else { ks[i] = 0ULL; ns[i] = 0x7FFFFFFF; }
    }
    __syncthreads();
    // 1) bitonic-sort every 64-run; final phase forced descending for ALL runs
    for (int k2 = 2; k2 <= 64; k2 <<= 1) {
        for (int j = k2 >> 1; j > 0; j >>= 1) {
            for (int i = tid; i < sl; i += 256) {
                int p = i ^ j;
                if (p > i) {
                    bool up = (k2 == 64) || ((i & k2) == 0);
                    bool gp = gt(ks[p], ns[p], ks[i], ns[i]);
                    if (gp == up) {
                        ull tk = ks[i]; ks[i] = ks[p]; ks[p] = tk;
                        int tn = ns[i]; ns[i] = ns[p]; ns[p] = tn;
                    }
                }
            }
            __syncthreads();
        }
    }
    // 2) merge tree: pairs of sorted-desc 64-runs -> top-64 (split pass + 6 merge passes)
    for (int S = 64, runs = sl >> 6; runs > 1; S <<= 1, runs >>= 1) {
        int tot = (runs >> 1) << 6;
        for (int t2 = tid; t2 < tot; t2 += 256) {
            int p = t2 >> 6, o = t2 & 63;
            int i1 = p * (S << 1) + o;
            int i2 = p * (S << 1) + S + 63 - o;     // reversed B — bitonic split
            if (gt(ks[i2], ns[i2], ks[i1], ns[i1])) {
                ull tk = ks[i1]; ks[i1] = ks[i2]; ks[i2] = tk;
                int tn = ns[i1]; ns[i1] = ns[i2]; ns[i2] = tn;
            }
        }
        __syncthreads();
        for (int j = 32; j > 0; j >>= 1) {
            for (int t2 = tid; t2 < tot; t2 += 256) {
                int p = t2 >> 6, o = t2 & 63;
                if ((o & j) == 0) {
                    int i1 = p * (S << 1) + o, i2 = i1 + j;
                    if (gt(ks[i2], ns[i2], ks[i1], ns[i1])) {
                        ull tk = ks[i1]; ks[i1] = ks[i2]; ks[i2] = tk;
                        int tn = ns[i1]; ns[i1] = ns[i2]; ns[i2] = tn;
                    }
                }
            }
            __syncthreads();
        }
    }
    for (int i = tid; i < KK; i += 256) {
        tkey[(long)c * MM + b * KK + i] = ks[i];
        tnode[(long)c * MM + b * KK + i] = ns[i];
    }
}

// -------------------- stage B: merge 32 sorted runs -> exact top-64 --------------------

__global__ __launch_bounds__(256)
void k_merge(const int* __restrict__ cnt,
             const ull* __restrict__ tkey, const int* __restrict__ tnode,
             const int* __restrict__ known, const unsigned* __restrict__ nbr,
             int* __restrict__ sel_idx, double* __restrict__ sel_prob, int cap) {
    __shared__ ull ks[MM];
    __shared__ int ns[MM];
    int c = blockIdx.x, tid = threadIdx.x;
    for (int i = tid; i < MM; i += 256) {
        ks[i] = tkey[(long)c * MM + i];
        ns[i] = tnode[(long)c * MM + i];
    }
    __syncthreads();
    for (int S = 64, runs = NB; runs > 1; S <<= 1, runs >>= 1) {
        int tot = (runs >> 1) << 6;
        for (int t2 = tid; t2 < tot; t2 += 256) {
            int p = t2 >> 6, o = t2 & 63;
            int i1 = p * (S << 1) + o;
            int i2 = p * (S << 1) + S + 63 - o;
            if (gt(ks[i2], ns[i2], ks[i1], ns[i1])) {
                ull tk = ks[i1]; ks[i1] = ks[i2]; ks[i2] = tk;
                int tn = ns[i1]; ns[i1] = ns[i2]; ns[i2] = tn;
            }
        }
        __syncthreads();
        for (int j = 32; j > 0; j >>= 1) {
            for (int t2 = tid; t2 < tot; t2 += 256) {
                int p = t2 >> 6, o = t2 & 63;
                if ((o & j) == 0) {
                    int i1 = p * (S << 1) + o, i2 = i1 + j;
                    if (gt(ks[i2], ns[i2], ks[i1], ns[i1])) {
                        ull tk = ks[i1]; ks[i1] = ks[i2]; ks[i2] = tk;
                        int tn = ns[i1]; ns[i1] = ns[i2]; ns[i2] = tn;
                    }
                }
            }
            __syncthreads();
        }
    }
    int count = min(cnt[c * CNT_STRIDE], cap);
    int nsel = min(count, KK);
    for (int i = tid; i < KK; i += 256) {
        if (i < nsel) {
            sel_idx[c * KK + i] = ns[i];
            sel_prob[c * KK + i] = keyord(ks[i]);
        }
    }
    // fill path (fewer valid than K): lowest-index invalid nodes, prob=-1e9
    if (tid == 0 && nsel < KK) {
        int r = nsel;
        for (int n = 0; n < NN && r < KK; ++n) {
            bool valid = ((nbr[n] >> c) & 1u) && !known[n];
            if (!valid) { sel_idx[c * KK + r] = n; sel_prob[c * KK + r] = -1e9; ++r; }
        }
    }
}

// -------------------- apply selections + write outputs --------------------

__global__ __launch_bounds__(256)
void k_upd(const int* __restrict__ sel_idx, const double* __restrict__ sel_prob,
           int* __restrict__ known, unsigned* __restrict__ cate,
           int* __restrict__ last, float* __restrict__ out, int t) {
    int i = blockIdx.x * blockDim.x + threadIdx.x;
    if (i >= CC * KK) return;
    int c = i / KK;
    int n = sel_idx[i];
    known[n] = 1;
    atomicOr(&cate[n], 1u << c);
    last[i] = n;
    out[t * CC * KK + i] = (float)sel_prob[i];               // outs
    out[NIT * CC * KK + t * CC * KK + i] = (float)n;         // exps as float
}

// -------------------- host launcher --------------------

extern "C" void kernel_launch(void* const* d_in, const int* in_sizes, int n_in,
                              void* d_out, int out_size, void* d_ws, size_t ws_size,
                              hipStream_t stream) {
    const float* es    = (const float*)d_in[0];
    const int*   edge  = (const int*)d_in[1];
    const int*   seeds = (const int*)d_in[2];
    const float* W     = (const float*)d_in[3];
    float* out = (float*)d_out;

    char* p = (char*)d_ws;
    auto alloc = [&](size_t bytes) -> char* {
        char* r = p;
        p += (bytes + 255) & ~(size_t)255;
        return r;
    };
    double*   inv_norm = (double*)alloc((size_t)NN * 8);
    int*      known    = (int*)alloc((size_t)NN * 4);
    unsigned* cate     = (unsigned*)alloc((size_t)NN * 4);
    unsigned* nbr      = (unsigned*)alloc((size_t)NN * 4);
    double*   hx       = (double*)alloc(CC * DD * 8);
    double*   hxn      = (double*)alloc(CC * DD * 8);
    int*      last     = (int*)alloc(CC * KK * 4);
    int*      sel_idx  = (int*)alloc(CC * KK * 4);
    double*   sel_prob = (double*)alloc(CC * KK * 8);
    int*      cnt      = (int*)alloc(CC * CNT_STRIDE * 4);
    ull*      tkey     = (ull*)alloc((size_t)CC * MM * 8);
    int*      tnode    = (int*)alloc((size_t)CC * MM * 4);
    size_t used = (size_t)(p - (char*)d_ws);
    size_t rem = (ws_size > used + 8192) ? (ws_size - used - 8192) : 0;
    long capl = (long)(rem / (CC * 12));
    if (capl > NN) capl = NN;
    if (capl < 1) capl = 1;
    int cap = (int)capl;
    int*    cidx   = (int*)alloc((size_t)CC * cap * 4);
    double* cscore = (double*)alloc((size_t)CC * cap * 8);

    k_norm<<<(NN + 3) / 4, 256, 0, stream>>>(es, inv_norm);
    k_zero<<<(NN + 255) / 256, 256, 0, stream>>>(known, cate, nbr);
    k_seed<<<1, 256, 0, stream>>>(seeds, known, cate);

    for (int t = 0; t < NIT; ++t) {
        k_mem<<<CC, 128, 0, stream>>>(es, W, seeds, last, hx, hxn, out, cnt, t);
        k_edge<<<(EE + 255) / 256, 256, 0, stream>>>(edge, cate, nbr);
        k_cand<<<(NN + 255) / 256, 256, 0, stream>>>(es, inv_norm, known, nbr, hxn,
                                                     cnt, cidx, cscore, cap);
        k_top<<<CC * NB, 256, 0, stream>>>(cnt, cidx, cscore, cap, tkey, tnode);
        k_merge<<<CC, 256, 0, stream>>>(cnt, tkey, tnode, known, nbr,
                                        sel_idx, sel_prob, cap);
        k_upd<<<4, 256, 0, stream>>>(sel_idx, sel_prob, known, cate, last, out, t);
    }
}

// Round 5
// 308.388 us; speedup vs baseline: 12.0161x; 1.2427x over previous
//
#include <hip/hip_runtime.h>
#include <math.h>

#define NN 100000
#define DD 128
#define CC 16
#define SS 16
#define EE 3200000
#define KK 64
#define NIT 4
#define CNT_STRIDE 32   // pad class counters 128B apart
#define NB 32           // stage-A blocks per class
#define SLMAX 4096      // max stage-A slice (pow2 >= ceil(NN/NB)=3125)
#define MM (NB * KK)    // stage-B merge size = 2048
#define EB ((EE + 255) / 256)
#define INF_STAMP 0x7fffffff

typedef unsigned long long ull;

// order-preserving double -> uint64 bijection (and exact inverse)
__device__ inline ull ordkey(double d) {
    long long b = __double_as_longlong(d);
    return (b < 0) ? ~(ull)b : ((ull)b | 0x8000000000000000ULL);
}
__device__ inline double keyord(ull u) {
    long long b = (u & 0x8000000000000000ULL)
                    ? (long long)(u & 0x7FFFFFFFFFFFFFFFULL)
                    : (long long)~u;
    return __longlong_as_double(b);
}
// total order: "a earlier than b" == key desc, node asc (== lax.top_k order)
__device__ inline bool gt(ull ka, int na, ull kb, int nb) {
    return (ka > kb) || (ka == kb && na < nb);
}

// in-wave bitonic sort of 64 (key,node) pairs, descending by gt. zero barriers.
__device__ inline void wsort64(ull& k, int& n, int lane) {
    for (int k2 = 2; k2 <= 64; k2 <<= 1) {
        for (int j = k2 >> 1; j; j >>= 1) {
            ull ok = __shfl_xor(k, j, 64);
            int on = __shfl_xor(n, j, 64);
            bool isLow = (lane & j) == 0;
            bool d = (k2 == 64) || ((lane & k2) == 0);
            bool wantMax = (d == isLow);
            if (wantMax == gt(ok, on, k, n)) { k = ok; n = on; }
        }
    }
}
// in-wave bitonic merge (input bitonic), descending by gt
__device__ inline void wmerge64(ull& k, int& n, int lane) {
    for (int j = 32; j; j >>= 1) {
        ull ok = __shfl_xor(k, j, 64);
        int on = __shfl_xor(n, j, 64);
        bool wantMax = (lane & j) == 0;
        if (wantMax == gt(ok, on, k, n)) { k = ok; n = on; }
    }
}

// -------------------- init: norms + state reset (fused) --------------------

__global__ __launch_bounds__(256)
void k_init(const float* __restrict__ es, double* __restrict__ inv_norm,
            int* __restrict__ known, unsigned* __restrict__ cate,
            unsigned* __restrict__ nbr) {
    int wave = threadIdx.x >> 6, lane = threadIdx.x & 63;
    int n = blockIdx.x * 4 + wave;
    if (n >= NN) return;
    float a = es[(long)n * DD + lane];
    float b = es[(long)n * DD + 64 + lane];
    double p = (double)a * (double)a + (double)b * (double)b;
    for (int o = 32; o > 0; o >>= 1) p += __shfl_xor(p, o, 64);
    if (lane == 0) {
        inv_norm[n] = 1.0 / (sqrt(p) + 1e-8);
        known[n] = INF_STAMP;
        cate[n] = 0;
        nbr[n] = 0;
    }
}

__global__ void k_seed(const int* __restrict__ seeds, int* __restrict__ known,
                       unsigned* __restrict__ cate) {
    int i = threadIdx.x;
    if (i < CC * SS) {
        int n = seeds[i];
        known[n] = 0;                       // stamp: known since iteration 0
        atomicOr(&cate[n], 1u << (i / SS));
    }
}

// ------------- fused: memory step (blocks 0..15) + edge pass (rest) -------------
// independent within an iteration: mem reads es/seeds/last/hx, edge reads cate -> nbr

__global__ __launch_bounds__(256)
void k_memedge(const float* __restrict__ es, const float* __restrict__ Wm,
               const int* __restrict__ seeds, const int* __restrict__ last,
               double* __restrict__ hx, double* __restrict__ hxn,
               float* __restrict__ out, int* __restrict__ cnt,
               const int* __restrict__ edge, const unsigned* __restrict__ cate,
               unsigned* __restrict__ nbr, int t) {
    __shared__ float  inp[KK][DD + 1];   // pad: conflict-free column reads
    __shared__ int    rowS[KK];
    __shared__ double q[DD];
    __shared__ double lg[KK];
    __shared__ double sr[KK];
    __shared__ double pre[DD];
    __shared__ double red[DD];
    int tid = threadIdx.x;

    if (blockIdx.x >= CC) {
        // ---- edge branch: nbr[dst] |= cate[src] ----
        long e = (long)(blockIdx.x - CC) * 256 + tid;
        if (e < EE) {
            int s = edge[e];
            unsigned m = cate[s];
            if (m) {
                int d = edge[EE + e];
                atomicOr(&nbr[d], m);
            }
        }
        return;
    }

    // ---- memory-step branch (block-uniform; barriers legal) ----
    int c = blockIdx.x;
    if (tid == 0) cnt[c * CNT_STRIDE] = 0;     // fused counter reset
    int k = (t == 0) ? SS : KK;
    if (tid < KK) {
        lg[tid] = -1.0e308;
        if (tid < k) rowS[tid] = (t == 0) ? seeds[c * SS + tid] : last[c * KK + tid];
    }
    __syncthreads();
    for (int i = tid; i < k * DD; i += 256)
        inp[i >> 7][i & 127] = es[(long)rowS[i >> 7] * DD + (i & 127)];
    __syncthreads();
    if (tid < DD) {
        if (t == 0) {
            double s = 0;
            for (int j = 0; j < k; ++j) s += (double)inp[j][tid];
            q[tid] = s / (double)k;
        } else {
            q[tid] = hx[c * DD + tid];
        }
    }
    __syncthreads();
    if (tid < k) {
        double s = 0;
        for (int i = 0; i < DD; ++i) s += (double)inp[tid][i] * q[i];
        lg[tid] = s / sqrt((double)DD);
    }
    __syncthreads();
    if (tid < KK) sr[tid] = lg[tid];
    __syncthreads();
    for (int st = 32; st > 0; st >>= 1) {
        if (tid < st) sr[tid] = fmax(sr[tid], sr[tid + st]);
        __syncthreads();
    }
    double mx = sr[0];
    __syncthreads();
    if (tid < KK) {
        double e = (tid < k) ? exp(lg[tid] - mx) : 0.0;
        lg[tid] = e; sr[tid] = e;
    }
    __syncthreads();
    for (int st = 32; st > 0; st >>= 1) {
        if (tid < st) sr[tid] += sr[tid + st];
        __syncthreads();
    }
    double sm = sr[0];
    __syncthreads();
    if (tid < KK) lg[tid] /= sm;
    __syncthreads();
    if (tid < DD) {
        double ctx = 0;
        for (int j = 0; j < k; ++j) ctx += lg[j] * (double)inp[j][tid];
        pre[tid] = (t == 0) ? ctx : (ctx + q[tid]);
    }
    __syncthreads();
    double h = 0;
    if (tid < DD) {
        for (int i = 0; i < DD; ++i) h += pre[i] * (double)Wm[i * DD + tid];
        h = tanh(h);
        red[tid] = h * h;
    }
    __syncthreads();
    for (int st = 64; st > 0; st >>= 1) {
        if (tid < st) red[tid] += red[tid + st];
        __syncthreads();
    }
    if (tid < DD) {
        double inv = 1.0 / (sqrt(red[0]) + 1e-8);
        hx[c * DD + tid] = h;
        hxn[c * DD + tid] = h * inv;
        out[2 * NIT * CC * KK + t * CC * DD + c * DD + tid] = (float)h;  // hxes
    }
}

// -------------------- candidate scoring: block-aggregated, thread-per-pair --------------------

__global__ __launch_bounds__(256)
void k_cand(const float* __restrict__ es, const double* __restrict__ inv_norm,
            const int* __restrict__ known, const unsigned* __restrict__ nbr,
            const double* __restrict__ hxn,
            int* __restrict__ cnt, int* __restrict__ cidx,
            ull* __restrict__ ckey, int cap, int t) {
    __shared__ int    pair[256 * 16];
    __shared__ short  prank[256 * 16];
    __shared__ double hxnL[CC * 129];
    __shared__ int    lcnt[CC];
    __shared__ int    base[CC];
    __shared__ int    npair;
    int tid = threadIdx.x;

    for (int i = tid; i < CC * DD; i += 256)
        hxnL[(i >> 7) * 129 + (i & 127)] = hxn[i];
    if (tid < CC) lcnt[tid] = 0;
    if (tid == 0) npair = 0;
    __syncthreads();

    int n = blockIdx.x * 256 + tid;
    unsigned m = 0;
    if (n < NN && known[n] > t) m = nbr[n];   // stamp > t  <=>  unknown at iter t
    while (m) {
        int c = __ffs(m) - 1;
        m &= m - 1;
        int r = atomicAdd(&lcnt[c], 1);
        int p = atomicAdd(&npair, 1);
        pair[p] = (n << 4) | c;
        prank[p] = (short)r;
    }
    __syncthreads();

    if (tid < CC && lcnt[tid] > 0)
        base[tid] = atomicAdd(&cnt[tid * CNT_STRIDE], lcnt[tid]);
    __syncthreads();

    int np = npair;
    for (int t2 = tid; t2 < np; t2 += 256) {
        int pk = pair[t2];
        int nn = pk >> 4, c = pk & 15;
        const float4* row = (const float4*)(es + (long)nn * DD);
        const double* h = &hxnL[c * 129];
        double s = 0;
        #pragma unroll
        for (int i = 0; i < 32; ++i) {
            float4 v = row[i];
            s += (double)v.x * h[4 * i + 0] + (double)v.y * h[4 * i + 1]
               + (double)v.z * h[4 * i + 2] + (double)v.w * h[4 * i + 3];
        }
        int pos = base[c] + (int)prank[t2];
        if (pos < cap) {
            cidx[(long)c * cap + pos] = nn;
            ckey[(long)c * cap + pos] = ordkey(s * inv_norm[nn]);
        }
    }
}

// ---------- stage A: per-slice exact top-64 (in-wave sorts + in-wave merge tree) ----------

__global__ __launch_bounds__(256)
void k_top(const int* __restrict__ cnt, const int* __restrict__ cidx,
           const ull* __restrict__ ckey, int cap,
           ull* __restrict__ tkey, int* __restrict__ tnode) {
    __shared__ ull ks[SLMAX];
    __shared__ int ns[SLMAX];
    int c = blockIdx.x / NB, b = blockIdx.x % NB;
    int tid = threadIdx.x, wave = tid >> 6, lane = tid & 63;
    int count = min(cnt[c * CNT_STRIDE], cap);
    int per = (count + NB - 1) / NB;
    int start = b * per;
    int m = min(per, count - start);
    int sl = 64;
    while (sl < per) sl <<= 1;
    int nruns = sl >> 6;
    // sort each 64-run inside one wave (registers, no barriers)
    for (int r = wave; r < nruns; r += 4) {
        int i = (r << 6) + lane;
        ull k; int n;
        if (i < m) { k = ckey[(long)c * cap + start + i]; n = cidx[(long)c * cap + start + i]; }
        else       { k = 0ULL; n = 0x7FFFFFFF; }
        wsort64(k, n, lane);
        ks[i] = k; ns[i] = n;
    }
    __syncthreads();
    // merge tree: each pair handled by one wave; winner written over run A
    for (int step = 1; step < nruns; step <<= 1) {
        int npair2 = nruns / (2 * step);
        for (int pr = wave; pr < npair2; pr += 4) {
            int ra = pr * 2 * step, rb = ra + step;
            ull ka = ks[(ra << 6) + lane];       int na = ns[(ra << 6) + lane];
            ull kb = ks[(rb << 6) + 63 - lane];  int nb2 = ns[(rb << 6) + 63 - lane];
            if (gt(kb, nb2, ka, na)) { ka = kb; na = nb2; }   // bitonic split -> winners
            wmerge64(ka, na, lane);
            ks[(ra << 6) + lane] = ka; ns[(ra << 6) + lane] = na;
        }
        __syncthreads();
    }
    if (tid < KK) {
        tkey[(long)c * MM + b * KK + tid] = ks[tid];
        tnode[(long)c * MM + b * KK + tid] = ns[tid];
    }
}

// ---------- stage B: merge 32 sorted runs -> top-64, apply updates + outputs (fused) ----------

__global__ __launch_bounds__(256)
void k_mergeupd(const int* __restrict__ cnt,
                const ull* __restrict__ tkey, const int* __restrict__ tnode,
                int* __restrict__ known, const unsigned* __restrict__ nbr,
                unsigned* __restrict__ cate, int* __restrict__ last,
                float* __restrict__ out, int cap, int t) {
    __shared__ ull ks[MM];
    __shared__ int ns[MM];
    int c = blockIdx.x, tid = threadIdx.x, wave = tid >> 6, lane = tid & 63;
    for (int i = tid; i < MM; i += 256) {
        ks[i] = tkey[(long)c * MM + i];
        ns[i] = tnode[(long)c * MM + i];
    }
    __syncthreads();
    for (int step = 1; step < NB; step <<= 1) {
        int npair2 = NB / (2 * step);
        for (int pr = wave; pr < npair2; pr += 4) {
            int ra = pr * 2 * step, rb = ra + step;
            ull ka = ks[(ra << 6) + lane];       int na = ns[(ra << 6) + lane];
            ull kb = ks[(rb << 6) + 63 - lane];  int nb2 = ns[(rb << 6) + 63 - lane];
            if (gt(kb, nb2, ka, na)) { ka = kb; na = nb2; }
            wmerge64(ka, na, lane);
            ks[(ra << 6) + lane] = ka; ns[(ra << 6) + lane] = na;
        }
        __syncthreads();
    }
    int count = min(cnt[c * CNT_STRIDE], cap);
    int nsel = min(count, KK);
    if (tid < KK && tid < nsel) {
        int n = ns[tid];
        out[t * CC * KK + c * KK + tid] = (float)keyord(ks[tid]);     // outs
        out[NIT * CC * KK + t * CC * KK + c * KK + tid] = (float)n;   // exps
        last[c * KK + tid] = n;
        known[n] = t + 1;               // stamp: invisible to this iteration's tests
        atomicOr(&cate[n], 1u << c);
    }
    // fill path (fewer valid than K): lowest-index invalid nodes, prob=-1e9.
    // stamp test (known[n] <= t) sees only pre-iteration state -> race-free vs
    // concurrent t+1 stamps from other classes (matches reference semantics).
    if (tid == 0 && nsel < KK) {
        int r = nsel;
        for (int n = 0; n < NN && r < KK; ++n) {
            bool valid = ((nbr[n] >> c) & 1u) && (known[n] > t);
            if (!valid) {
                out[t * CC * KK + c * KK + r] = -1e9f;
                out[NIT * CC * KK + t * CC * KK + c * KK + r] = (float)n;
                last[c * KK + r] = n;
                known[n] = t + 1;
                atomicOr(&cate[n], 1u << c);
                ++r;
            }
        }
    }
}

// -------------------- host launcher --------------------

extern "C" void kernel_launch(void* const* d_in, const int* in_sizes, int n_in,
                              void* d_out, int out_size, void* d_ws, size_t ws_size,
                              hipStream_t stream) {
    const float* es    = (const float*)d_in[0];
    const int*   edge  = (const int*)d_in[1];
    const int*   seeds = (const int*)d_in[2];
    const float* W     = (const float*)d_in[3];
    float* out = (float*)d_out;

    char* p = (char*)d_ws;
    auto alloc = [&](size_t bytes) -> char* {
        char* r = p;
        p += (bytes + 255) & ~(size_t)255;
        return r;
    };
    double*   inv_norm = (double*)alloc((size_t)NN * 8);
    int*      known    = (int*)alloc((size_t)NN * 4);
    unsigned* cate     = (unsigned*)alloc((size_t)NN * 4);
    unsigned* nbr      = (unsigned*)alloc((size_t)NN * 4);
    double*   hx       = (double*)alloc(CC * DD * 8);
    double*   hxn      = (double*)alloc(CC * DD * 8);
    int*      last     = (int*)alloc(CC * KK * 4);
    int*      cnt      = (int*)alloc(CC * CNT_STRIDE * 4);
    ull*      tkey     = (ull*)alloc((size_t)CC * MM * 8);
    int*      tnode    = (int*)alloc((size_t)CC * MM * 4);
    size_t used = (size_t)(p - (char*)d_ws);
    size_t rem = (ws_size > used + 8192) ? (ws_size - used - 8192) : 0;
    long capl = (long)(rem / (CC * 12));
    if (capl > NN) capl = NN;
    if (capl < 1) capl = 1;
    int cap = (int)capl;
    int*    cidx = (int*)alloc((size_t)CC * cap * 4);
    ull*    ckey = (ull*)alloc((size_t)CC * cap * 8);

    k_init<<<(NN + 3) / 4, 256, 0, stream>>>(es, inv_norm, known, cate, nbr);
    k_seed<<<1, 256, 0, stream>>>(seeds, known, cate);

    for (int t = 0; t < NIT; ++t) {
        k_memedge<<<CC + EB, 256, 0, stream>>>(es, W, seeds, last, hx, hxn, out,
                                               cnt, edge, cate, nbr, t);
        k_cand<<<(NN + 255) / 256, 256, 0, stream>>>(es, inv_norm, known, nbr, hxn,
                                                     cnt, cidx, ckey, cap, t);
        k_top<<<CC * NB, 256, 0, stream>>>(cnt, cidx, ckey, cap, tkey, tnode);
        k_mergeupd<<<CC, 256, 0, stream>>>(cnt, tkey, tnode, known, nbr,
                                           cate, last, out, cap, t);
    }
}